// Round 3
// baseline (121.185 us; speedup 1.0000x reference)
//
#include <hip/hip_runtime.h>

// MXIntSoftmax — bit-exact integer port, round 3 (R2 + shadowing fix).
//
// Collapsed reference semantics (verified absmax=0 in R1):
//   per elem: e = clip(ebits-127+(mant!=0), -8, 7)         [== clip(ceil(log2|x|))]
//             mi = clip(rne(x * 2^(7-e)), -128, 127)
//             yq = clip((mi*46) >> (7-e), -256, 255)       [floor, arithmetic shift]
//             ee = yq>>5 in [-8,7]; me = TAB[yq&31] in [64,125]
//   scan collapses to one floor:
//             E_i = running prefix max of ee; term_i = ((me_i<<4) >> (E_i-ee_i)) << (E_i+8)
//             msum = (sum_i term_i) >> (Estar+8)  >= 1024,  < 2^23
//   out: mout = floor(me*256/msum) in [0,31]  -> magic multiply (exact: n*d < 2^38)
//        final mxint quant: clog=ceil(log2 mout); s=min(7-clog, eout+11);
//        m2 = rne_halfeven(mout*2^s) clipped at 127; ef=max(clog+eout-4,-8); o=m2*2^(ef-7)

#define D_DIM 2048
#define TPB   256
#define EPT   8

__device__ __constant__ int c_mexp_tab[32] = {
    64, 65, 67, 68, 70, 71, 73, 74, 76, 78, 79, 81, 83, 85, 87, 89,
    91, 92, 95, 97, 99, 101, 103, 105, 108, 110, 112, 115, 117, 120, 123, 125
};

__global__ __launch_bounds__(TPB) void mxint_softmax_kernel(const float* __restrict__ x,
                                                            float* __restrict__ out) {
    const int t    = threadIdx.x;
    const int lane = t & 63;
    const int wid  = t >> 6;

    __shared__ int                s_wmax[4];
    __shared__ unsigned long long s_wsum[4];

    // lane l holds TAB[l&31]; gather later via conflict-free ds_bpermute (no LDS, no barrier)
    const int tv = c_mexp_tab[lane & 31];

    const size_t base = (size_t)blockIdx.x * D_DIM + (size_t)t * EPT;
    const float4 v0 = *(const float4*)(x + base);
    const float4 v1 = *(const float4*)(x + base + 4);
    const float xs[8] = {v0.x, v0.y, v0.z, v0.w, v1.x, v1.y, v1.z, v1.w};

    int pk[8];          // me | ((ee+8)<<8), fits 12 bits
    int run = -8;       // identity for max over ee (ee >= -8 always)
#pragma unroll
    for (int j = 0; j < 8; ++j) {
        const float    xv   = xs[j];
        const unsigned bits = __float_as_uint(xv) & 0x7fffffffu;
        // ceil(log2|x|) clip [-8,7]; zeros/subnormals fall to e=-8 and mi=0 -> yq=0 (matches ref)
        int e = (int)(bits >> 23) - 127 + (((bits & 0x7fffffu) != 0u) ? 1 : 0);
        e = min(7, max(-8, e));
        const float su = __uint_as_float((unsigned)(134 - e) << 23);   // 2^(7-e), exact
        int mi = (int)rintf(xv * su);                                  // |.| <= 128, half-even
        mi = min(127, max(-128, mi));
        int yq = (mi * 46) >> (7 - e);                                 // floor(mi*46*2^(e-7))
        yq = min(255, max(-256, yq));
        const int ee = yq >> 5;
        const int me = __builtin_amdgcn_ds_bpermute((yq & 31) << 2, tv);
        pk[j] = me | ((ee + 8) << 8);
        run   = max(run, ee);
    }

    // ---- exclusive prefix max across block (thread order == element order) ----
    int v = run;
#pragma unroll
    for (int d = 1; d < 64; d <<= 1) {
        const int o = __shfl_up(v, d, 64);
        if (lane >= d) v = max(v, o);
    }
    if (lane == 63) s_wmax[wid] = v;     // per-wave max
    __syncthreads();

    int wpref = -8;
#pragma unroll
    for (int w = 0; w < 4; ++w)
        if (w < wid) wpref = max(wpref, s_wmax[w]);
    int ex = __shfl_up(v, 1, 64);
    if (lane == 0) ex = -8;
    const int P = max(wpref, ex);        // exclusive prefix max for this thread

    // ---- weighted integer sum (collapsed scan), u32 per-thread partial ----
    unsigned partial = 0;                // terms < 2^26, 8 of them -> < 2^29
    int E = P;
#pragma unroll
    for (int j = 0; j < 8; ++j) {
        const int ee = (pk[j] >> 8) - 8;
        const int me = pk[j] & 0xff;
        E = max(E, ee);                                  // inclusive running max
        const unsigned c = ((unsigned)me << 4) >> (E - ee);
        partial += c << (E + 8);                         // E+8 in [0,15]
    }

    // wave reduce: 3 levels u32 (8-lane sums <= 4.19e9 < 2^32), then u64
    unsigned p32 = partial;
    p32 += __shfl_down(p32, 32, 64);
    p32 += __shfl_down(p32, 16, 64);
    p32 += __shfl_down(p32, 8, 64);
    unsigned long long p64 = p32;
    p64 += __shfl_down(p64, 4, 64);
    p64 += __shfl_down(p64, 2, 64);
    p64 += __shfl_down(p64, 1, 64);
    if (lane == 0) s_wsum[wid] = p64;
    __syncthreads();

    const unsigned long long total = s_wsum[0] + s_wsum[1] + s_wsum[2] + s_wsum[3];
    const int Estar = max(max(s_wmax[0], s_wmax[1]), max(s_wmax[2], s_wmax[3]));
    const unsigned msum = (unsigned)(total >> (Estar + 8));   // in [1024, 2^23)

    // magic = floor(2^38/msum)+1 via two u32 divides (once per thread, uniform)
    const unsigned mq    = 0x80000000u / msum;                // floor(2^31/msum) < 2^21
    const unsigned mr    = 0x80000000u - mq * msum;           // < msum < 2^23
    const unsigned magic = (mq << 7) + ((mr << 7) / msum) + 1u;

    // ---- per-element division (magic mul) + branchless final mxint quant ----
    float res[8];
#pragma unroll
    for (int j = 0; j < 8; ++j) {
        const int      me   = pk[j] & 0xff;
        const int      ee   = (pk[j] >> 8) - 8;
        const unsigned num  = (unsigned)(me << 8);            // <= 32000
        const unsigned mout = (unsigned)(((unsigned long long)num * magic) >> 38);  // exact floor
        const int eout = ee - Estar;                          // [-15, 0]
        const int bl   = 32 - __clz((int)(mout | 1u));
        const int pw2  = ((mout & (mout - 1u)) == 0u) ? 1 : 0;
        const int clog = bl - pw2;                            // ceil(log2 mout), 0 for mout<=1
        const int s    = min(7 - clog, eout + 11);            // in [-4, 7]
        const int rs   = 8 - s;                               // in [1, 12]
        const unsigned u    = mout << 8;
        const unsigned bse  = u >> rs;
        const unsigned frac = u & ((1u << rs) - 1u);
        const unsigned half = 1u << (rs - 1);
        unsigned m2 = bse + (((frac > half) || (frac == half && (bse & 1u))) ? 1u : 0u);
        m2 = min(m2, 127u);                                   // 128 (pow2 full-scale) -> 127
        const int ef = max(clog + eout - 4, -8);              // in [-8, 1]
        res[j] = (float)m2 * __uint_as_float((unsigned)(ef + 120) << 23);  // m2 * 2^(ef-7)
    }

    const float4 out0 = {res[0], res[1], res[2], res[3]};
    const float4 out1 = {res[4], res[5], res[6], res[7]};
    *(float4*)(out + base)     = out0;
    *(float4*)(out + base + 4) = out1;
}

extern "C" void kernel_launch(void* const* d_in, const int* in_sizes, int n_in,
                              void* d_out, int out_size, void* d_ws, size_t ws_size,
                              hipStream_t stream) {
    const float* x   = (const float*)d_in[0];
    float*       o   = (float*)d_out;
    const int rows = in_sizes[0] / D_DIM;   // 8192
    mxint_softmax_kernel<<<rows, TPB, 0, stream>>>(x, o);
}

// Round 4
// 114.072 us; speedup vs baseline: 1.0624x; 1.0624x over previous
//
#include <hip/hip_runtime.h>

// MXIntSoftmax — bit-exact integer port, round 4: wave-per-row restructure.
//
// Collapsed reference semantics (verified absmax=0 in R1/R3):
//   per elem: eb = ((bits&0x7fffffff)+0x7fffff)>>23  [biased ceil(log2|x|)]
//             ebc = clip(eb, 119, 134)               [e = ebc-127 in [-8,7]]
//             mi  = clip(rne(x * 2^(134-ebc-127)), -128, 127)
//             yq  = clip((mi*46) >> (134-ebc), -256, 255)
//             ee8 = (yq>>5)+8 in [0,15]; me = TAB[yq&31] in [64,125]
//   scan collapses to one floor (E8 = biased running prefix max, order = row order):
//             partial += (((me<<4) >> (E8-ee8)) << E8);  msum = (sum) >> Estar8  (>=1024, <2^22)
//   out: mout = floor(me*256/msum) in [0,31] via magic mul (exact, n*d < 2^43, magic<2^28+1)
//        final mxint quant is a pure function of (mout, eoutn=Estar8-ee8) -> 512-entry table.
//
// One wave per row: no __syncthreads, no cross-wave LDS. 4 rows per 256-thread block.

#define D_DIM 2048
#define TPB   256
#define RPB   4      // rows (waves) per block

__device__ __constant__ int c_mexp_tab[32] = {
    64, 65, 67, 68, 70, 71, 73, 74, 76, 78, 79, 81, 83, 85, 87, 89,
    91, 92, 95, 97, 99, 101, 103, 105, 108, 110, 112, 115, 117, 120, 123, 125
};

__global__ __launch_bounds__(TPB) void mxint_softmax_kernel(const float* __restrict__ x,
                                                            float* __restrict__ out) {
    const int t    = threadIdx.x;
    const int lane = t & 63;
    const int wid  = t >> 6;
    const int row  = blockIdx.x * RPB + wid;

    __shared__ float s_res[RPB][512];
    float* wt = s_res[wid];            // per-wave table: no cross-wave sharing, no barrier

    // ---- per-wave build of the output table: res(mout, eoutn), 8 entries/lane ----
#pragma unroll
    for (int q = 0; q < 8; ++q) {
        const int      idx   = q * 64 + lane;            // 0..511
        const unsigned mout  = (unsigned)(idx & 31);
        const int      eoutn = idx >> 5;                 // eout = -eoutn, [0,15]
        const int      bl    = 32 - __clz((int)(mout | 1u));
        const int      pw2   = ((mout & (mout - 1u)) == 0u) ? 1 : 0;
        const int      clog  = bl - pw2;                 // ceil(log2 mout), 0 for mout<=1
        const int      s     = min(7 - clog, 11 - eoutn);
        const int      rs    = 8 - s;                    // [1,12]
        const unsigned u     = mout << 8;
        const unsigned bse   = u >> rs;
        const unsigned frac  = u & ((1u << rs) - 1u);
        const unsigned half  = 1u << (rs - 1);
        unsigned m2 = bse + (((frac > half) || (frac == half && (bse & 1u))) ? 1u : 0u);
        m2 = min(m2, 127u);                              // 128 -> 127
        const int ef = max(clog - eoutn - 4, -8);
        wt[idx] = (float)m2 * __uint_as_float((unsigned)(ef + 120) << 23);  // m2 * 2^(ef-7)
    }

    // mexp table seed for ds_bpermute (lanes 0..31 hold TAB, 32..63 duplicate)
    const int tv = c_mexp_tab[lane & 31];

    // ---- coalesced row load: round i, lane l -> elements i*256 + l*4 .. +3 ----
    const float* xr = x + (size_t)row * D_DIM;
    float4 v[8];
#pragma unroll
    for (int i = 0; i < 8; ++i)
        v[i] = *(const float4*)(xr + i * 256 + lane * 4);

    unsigned pk[16];        // 2 elems per entry: me|ee8<<8 | me<<16|ee8<<24
    unsigned partial = 0;   // 32 terms <= 6.554e7 each -> < 2.1e9, u32 safe
    int carry8 = 0;         // biased running max across rounds (0 == e=-8 identity)

#pragma unroll
    for (int i = 0; i < 8; ++i) {
        const float xs4[4] = {v[i].x, v[i].y, v[i].z, v[i].w};
        int me[4], e8[4], a[4];
#pragma unroll
        for (int k = 0; k < 4; ++k) {
            const float    xv   = xs4[k];
            const unsigned bits = __float_as_uint(xv) & 0x7fffffffu;
            const int      eb   = (int)((bits + 0x7fffffu) >> 23);   // biased ceil(log2)
            const int      ebc  = min(134, max(119, eb));
            const float    su   = __uint_as_float((unsigned)(261 - ebc) << 23); // 2^(7-e)
            int mi = (int)rintf(xv * su);                             // half-even
            mi = min(127, max(-128, mi));
            int yq = (mi * 46) >> (134 - ebc);                        // floor
            yq = min(255, max(-256, yq));
            e8[k] = (yq >> 5) + 8;                                    // [0,15]
            me[k] = __builtin_amdgcn_ds_bpermute((yq & 31) << 2, tv);
            a[k]  = (k == 0) ? e8[0] : max(a[k - 1], e8[k]);          // in-lane incl prefix
        }

        // wave inclusive scan of lane round-max (element order within round = lane-major)
        int sc = a[3];
#pragma unroll
        for (int d = 1; d < 64; d <<= 1) {
            const int o = __shfl_up(sc, d, 64);
            if (lane >= d) sc = max(sc, o);
        }
        int ex = __shfl_up(sc, 1, 64);
        if (lane == 0) ex = 0;
        const int base = max(carry8, ex);     // biased exclusive prefix for this lane/round

#pragma unroll
        for (int k = 0; k < 4; ++k) {
            const int E8 = max(base, a[k]);                           // elem's prefix max
            const unsigned c = ((unsigned)me[k] << 4) >> (E8 - e8[k]);
            partial += c << E8;                                       // shift = E+8 = E8
        }
        pk[2 * i]     = (unsigned)me[0] | ((unsigned)e8[0] << 8)
                      | ((unsigned)me[1] << 16) | ((unsigned)e8[1] << 24);
        pk[2 * i + 1] = (unsigned)me[2] | ((unsigned)e8[2] << 8)
                      | ((unsigned)me[3] << 16) | ((unsigned)e8[3] << 24);

        carry8 = max(carry8, __shfl(sc, 63, 64));                     // round total max
    }

    // ---- wave butterfly reduce (u64): all lanes get the total ----
    unsigned long long p64 = partial;
#pragma unroll
    for (int d = 32; d >= 1; d >>= 1) p64 += __shfl_xor(p64, d, 64);

    const int      Estar8 = carry8;                    // uniform across lanes
    const unsigned msum   = (unsigned)(p64 >> Estar8); // in [1024, 2^22)
    // magic = floor(2^38/msum)+1 ; f64 path exact (distance to integer >= 1/msum > f64 err)
    const unsigned magic  = (unsigned)(274877906944.0 / (double)msum) + 1u;

    // ---- epilogue: magic division + table lookup, coalesced float4 stores ----
    float* orow = out + (size_t)row * D_DIM;
#pragma unroll
    for (int i = 0; i < 8; ++i) {
        float r4[4];
#pragma unroll
        for (int k = 0; k < 4; ++k) {
            const unsigned p   = pk[2 * i + (k >> 1)];
            const unsigned sh  = (unsigned)(k & 1) * 16u;
            const unsigned mel = (p >> sh) & 0xffu;
            const unsigned ee8 = (p >> (sh + 8)) & 0xffu;
            const unsigned mout  = __umulhi(mel << 8, magic) >> 6;    // floor(me*256/msum)
            const int      eoutn = Estar8 - (int)ee8;                 // [0,15]
            r4[k] = wt[(eoutn << 5) | (int)mout];
        }
        const float4 o4 = {r4[0], r4[1], r4[2], r4[3]};
        *(float4*)(orow + i * 256 + lane * 4) = o4;
    }
}

extern "C" void kernel_launch(void* const* d_in, const int* in_sizes, int n_in,
                              void* d_out, int out_size, void* d_ws, size_t ws_size,
                              hipStream_t stream) {
    const float* x = (const float*)d_in[0];
    float*       o = (float*)d_out;
    const int rows = in_sizes[0] / D_DIM;      // 8192
    mxint_softmax_kernel<<<rows / RPB, TPB, 0, stream>>>(x, o);
}

// Round 5
// 113.743 us; speedup vs baseline: 1.0654x; 1.0029x over previous
//
#include <hip/hip_runtime.h>

// MXIntSoftmax — bit-exact integer port, round 5: wave-per-row, single packed scan.
//
// Collapsed reference semantics (verified absmax=0 in R1/R3/R4):
//   per elem: eb = ((bits&0x7fffffff)+0x7fffff)>>23 ; ebc = clip(eb,119,134)
//             mi = clip(rne(x*2^(134-ebc)), -128,127) ; yq = clip((mi*46)>>(134-ebc), -256,255)
//             e8 = (yq>>5)+8 in [0,15] ; me = rint(exp2((yq&31)/32 + 6)) in [64,125]
//               (v_exp_f32 <=1ulp; nearest half-integer boundary 0.0169 away -> exact TAB match)
//   collapsed scan (E8 = biased running prefix max over row order):
//             partial += ((me<<4) >> (E8-e8)) << E8 ;  msum = total >> Estar8  (in [1024,2^22))
//   mout = floor(me*256/msum) via magic mul (exact) ; output = table(mout, Estar8-e8).
//
// One wave per row (4 rows / 256-thread block), zero barriers. Prefix-max over
// lanes for ALL 8 rounds at once: 8 per-round lane-maxima packed as bytes in
// 2 u32, one 6-step wave scan with SWAR byte-max (values<=15, no borrow).

#define D_DIM 2048
#define TPB   256
#define RPB   4

// byte-wise max of two u32 whose bytes are all < 128 (here: <= 15)
__device__ __forceinline__ unsigned bmax4(unsigned x, unsigned y) {
    const unsigned d     = (x | 0x80808080u) - y;          // per-byte 0x80+x-y, no borrow
    const unsigned flags = d & 0x80808080u;                // 0x80 where x >= y
    const unsigned mask  = (flags - (flags >> 7)) | flags; // 0xFF where x >= y
    return (x & mask) | (y & ~mask);                       // v_bfi_b32
}

__global__ __launch_bounds__(TPB) void mxint_softmax_kernel(const float* __restrict__ x,
                                                            float* __restrict__ out) {
    const int t    = threadIdx.x;
    const int lane = t & 63;
    const int wid  = t >> 6;
    const int row  = blockIdx.x * RPB + wid;

    // ---- issue global loads first (coalesced: round i, lane l -> elems i*256+l*4..+3) ----
    const float* xr = x + (size_t)row * D_DIM;
    float4 v[8];
#pragma unroll
    for (int i = 0; i < 8; ++i)
        v[i] = *(const float4*)(xr + i * 256 + lane * 4);

    // ---- per-wave epilogue table res(mout, eoutn): built while loads are in flight ----
    __shared__ float s_res[RPB][512];
    float* wt = s_res[wid];                    // same wave writes & reads: no barrier
#pragma unroll
    for (int q = 0; q < 8; ++q) {
        const int      idx   = q * 64 + lane;            // 0..511
        const unsigned mout  = (unsigned)(idx & 31);
        const int      eoutn = idx >> 5;                 // eout = -eoutn in [0,15]
        const int      bl    = 32 - __clz((int)(mout | 1u));
        const int      pw2   = ((mout & (mout - 1u)) == 0u) ? 1 : 0;
        const int      clog  = bl - pw2;                 // ceil(log2 mout)
        const int      s     = min(7 - clog, 11 - eoutn);
        const int      rs    = 8 - s;                    // [1,12]
        const unsigned u     = mout << 8;
        const unsigned bse   = u >> rs;
        const unsigned frac  = u & ((1u << rs) - 1u);
        const unsigned half  = 1u << (rs - 1);
        unsigned m2 = bse + (((frac > half) || (frac == half && (bse & 1u))) ? 1u : 0u);
        m2 = min(m2, 127u);                              // 128 -> 127
        const int ef = max(clog - eoutn - 4, -8);
        wt[idx] = (float)m2 * __uint_as_float((unsigned)(ef + 120) << 23);
    }

    // ---- front end: me,e8 per element; per-round lane maxima packed as bytes ----
    unsigned pk[16];                 // 2 elems per u32: me | e8<<8 | me<<16 | e8<<24
    unsigned pe0 = 0, pe1 = 0;       // rounds 0-3 / 4-7 lane-maxima, 1 byte each
#pragma unroll
    for (int i = 0; i < 8; ++i) {
        const float xs4[4] = {v[i].x, v[i].y, v[i].z, v[i].w};
        int me[4], e8[4];
        int rmax = 0;
#pragma unroll
        for (int k = 0; k < 4; ++k) {
            const float    xv   = xs4[k];
            const unsigned bits = __float_as_uint(xv) & 0x7fffffffu;
            const int      eb   = (int)((bits + 0x7fffffu) >> 23);   // biased ceil(log2)
            const int      ebc  = min(134, max(119, eb));
            const float    su   = __uint_as_float((unsigned)(261 - ebc) << 23); // 2^(7-e)
            int mi = (int)rintf(xv * su);                             // half-even
            mi = min(127, max(-128, mi));
            int yq = (mi * 46) >> (134 - ebc);                        // floor
            yq = min(255, max(-256, yq));
            e8[k] = (yq >> 5) + 8;                                    // [0,15]
            // me = rint(2^((yq&31)/32) * 64) -- exact (17x margin vs 1ulp exp)
            const float a = fmaf((float)(yq & 31), 0.03125f, 6.0f);
            me[k] = (int)rintf(__builtin_amdgcn_exp2f(a));
            rmax  = max(rmax, e8[k]);
        }
        if (i < 4) pe0 |= (unsigned)rmax << (i * 8);
        else       pe1 |= (unsigned)rmax << ((i - 4) * 8);
        pk[2 * i]     = (unsigned)me[0] | ((unsigned)e8[0] << 8)
                      | ((unsigned)me[1] << 16) | ((unsigned)e8[1] << 24);
        pk[2 * i + 1] = (unsigned)me[2] | ((unsigned)e8[2] << 8)
                      | ((unsigned)me[3] << 16) | ((unsigned)e8[3] << 24);
    }

    // ---- ONE wave inclusive scan (byte-wise max, all 8 rounds at once) ----
    unsigned s0 = pe0, s1 = pe1;
#pragma unroll
    for (int d = 1; d < 64; d <<= 1) {
        const unsigned o0 = __shfl_up(s0, d, 64);
        const unsigned o1 = __shfl_up(s1, d, 64);
        if (lane >= d) { s0 = bmax4(s0, o0); s1 = bmax4(s1, o1); }
    }
    unsigned ex0 = __shfl_up(s0, 1, 64), ex1 = __shfl_up(s1, 1, 64);
    if (lane == 0) { ex0 = 0; ex1 = 0; }
    const unsigned bc0 = __shfl(s0, 63, 64), bc1 = __shfl(s1, 63, 64);  // round totals

    // ---- collapsed weighted sum (u32 per-lane; 32 terms <= 2.1e9) ----
    unsigned partial = 0;
    int crun = 0;                    // cumulative max of rounds < i (biased, 0 = e=-8)
#pragma unroll
    for (int i = 0; i < 8; ++i) {
        const unsigned exw = (i < 4) ? ex0 : ex1;
        const unsigned bcw = (i < 4) ? bc0 : bc1;
        const int      sh8 = (i & 3) * 8;
        const int      sx  = (int)((exw >> sh8) & 0xffu);   // excl lane-prefix, round i
        const int base = max(crun, sx);
        int ar = 0;
#pragma unroll
        for (int k = 0; k < 4; ++k) {
            const unsigned p  = pk[2 * i + (k >> 1)];
            const unsigned ss = (unsigned)(k & 1) * 16u;
            const int      mev = (int)((p >> ss) & 0xffu);
            const int      e8v = (int)((p >> (ss + 8)) & 0xffu);
            ar = max(ar, e8v);
            const int E8 = max(base, ar);                    // elem inclusive prefix max
            partial += (((unsigned)mev << 4) >> (E8 - e8v)) << E8;
        }
        crun = max(crun, (int)((bcw >> sh8) & 0xffu));
    }

    // ---- butterfly reduce: 1 step u32 (pair sums < 2^32), then u64 ----
    const unsigned ps = partial + __shfl_xor(partial, 1, 64);
    unsigned long long p64 = ps;
#pragma unroll
    for (int d = 2; d < 64; d <<= 1) p64 += __shfl_xor(p64, d, 64);

    const int      Estar8 = crun;                               // uniform = global max
    const unsigned msum   = (unsigned)(p64 >> Estar8);          // [1024, 2^22)
    // magic = floor(2^38/msum)+1 ; f64 path exact (dist to integer >= 1/msum >> f64 err)
    const unsigned magic  = (unsigned)(274877906944.0 / (double)msum) + 1u;

    // ---- epilogue: magic division + per-wave table lookup, coalesced stores ----
    float* orow = out + (size_t)row * D_DIM;
#pragma unroll
    for (int i = 0; i < 8; ++i) {
        float r4[4];
#pragma unroll
        for (int k = 0; k < 4; ++k) {
            const unsigned p   = pk[2 * i + (k >> 1)];
            const unsigned ss  = (unsigned)(k & 1) * 16u;
            const unsigned mel = (p >> ss) & 0xffu;
            const unsigned ee8 = (p >> (ss + 8)) & 0xffu;
            const unsigned mout  = __umulhi(mel << 8, magic) >> 6;  // floor(me*256/msum)
            const int      eoutn = Estar8 - (int)ee8;               // [0,15]
            r4[k] = wt[(eoutn << 5) | (int)mout];
        }
        const float4 o4 = {r4[0], r4[1], r4[2], r4[3]};
        *(float4*)(orow + i * 256 + lane * 4) = o4;
    }
}

extern "C" void kernel_launch(void* const* d_in, const int* in_sizes, int n_in,
                              void* d_out, int out_size, void* d_ws, size_t ws_size,
                              hipStream_t stream) {
    const float* x = (const float*)d_in[0];
    float*       o = (float*)d_out;
    const int rows = in_sizes[0] / D_DIM;      // 8192
    mxint_softmax_kernel<<<rows / RPB, TPB, 0, stream>>>(x, o);
}

// Round 6
// 109.665 us; speedup vs baseline: 1.1050x; 1.0372x over previous
//
#include <hip/hip_runtime.h>

// MXIntSoftmax — bit-exact integer port, round 6: 2 waves/row, 16 elems/thread.
//
// Semantics (verified absmax=0 in R1/R3/R4/R5):
//   yq    = clip(floor(clip(rne(x*2^(7-e)),-128,127) * 46 * 2^(e-7+5)), -256, 255),
//           e = clip(ceil(log2|x|),-8,7)  — done via exponent-field bit math + f32 (exact)
//   e8    = (yq>>5)+8 in [0,15] ; me = rint(exp2((yq&31)/32+6)) in [64,125]
//   scan  -> single floor: partial += ((me<<4) >> (E8-e8)) << E8, E8 = prefix max of e8
//   msum  = total >> Estar8 in [1024,2^22) ; magic = floor(2^38/msum)+1 (f64, exact)
//   out   = finalLUT[yq+256] where finalLUT fuses mout=floor(me*256/msum) and mxint quant.

#define D_DIM 2048
#define TPB   256

// byte-wise max of two u32 whose bytes are <= 15
__device__ __forceinline__ unsigned bmax4(unsigned x, unsigned y) {
    const unsigned d     = (x | 0x80808080u) - y;
    const unsigned flags = d & 0x80808080u;
    const unsigned mask  = (flags - (flags >> 7)) | flags;
    return (x & mask) | (y & ~mask);
}

__global__ __launch_bounds__(TPB, 6) void mxint_softmax_kernel(const float* __restrict__ x,
                                                               float* __restrict__ out) {
    const int t    = threadIdx.x;
    const int lane = t & 63;
    const int wid  = t >> 6;           // 4 waves: (0,1)->row0, (2,3)->row1
    const int half = wid & 1;
    const int r    = wid >> 1;
    const int row  = blockIdx.x * 2 + r;

    __shared__ unsigned short     s_pk[512];       // me<<4 keyed by yq+256 (static)
    __shared__ float              s_fin[2][512];   // per-row fused output LUT
    __shared__ int                s_rmax[4];       // per-wave max e8 (biased)
    __shared__ unsigned long long s_part[4];       // per-wave partial sums

    // ---- issue global loads first: thread covers 4 rounds x float4 ----
    const size_t base = (size_t)row * D_DIM + half * 1024 + lane * 4;
    float4 v[4];
#pragma unroll
    for (int i = 0; i < 4; ++i)
        v[i] = *(const float4*)(x + base + i * 256);

    // ---- static pk LUT: 2 entries/thread, overlaps load latency ----
#pragma unroll
    for (int q = 0; q < 2; ++q) {
        const int idx = t + 256 * q;
        const float a = fmaf((float)(idx & 31), 0.03125f, 6.0f);
        const int  me = (int)rintf(__builtin_amdgcn_exp2f(a));   // exact TAB match (17x margin)
        s_pk[idx] = (unsigned short)(me << 4);
    }

    // ---- front end: yq per element; per-round maxima packed as bytes ----
    int yq[16];
    unsigned pe = 0;
#pragma unroll
    for (int i = 0; i < 4; ++i) {
        const float xs4[4] = {v[i].x, v[i].y, v[i].z, v[i].w};
        int rmaxr = -256;
#pragma unroll
        for (int k = 0; k < 4; ++k) {
            const unsigned b  = __float_as_uint(xs4[k]) & 0x7fffffffu;
            const unsigned tb = b + 0x7fffffu;
            const unsigned tc = min(max(tb, 0x3B800000u), 0x43000000u);  // clamp exp field
            const unsigned es = tc & 0xFF800000u;                        // ebc<<23
            const float    su  = __uint_as_float(0x82800000u - es);      // 2^(134-ebc)
            const float    fac = __uint_as_float(es + 0xFF380000u);      // 46*2^(ebc-134)
            const float    mi  = __builtin_amdgcn_fmed3f(rintf(xs4[k] * su), -128.0f, 127.0f);
            int y = (int)floorf(mi * fac);                               // exact product
            y = min(255, max(-256, y));
            yq[4 * i + k] = y;
            rmaxr = max(rmaxr, y);
        }
        pe |= (unsigned)((rmaxr >> 5) + 8) << (8 * i);     // biased e8 round-max byte
    }

    // ---- one SWAR wave scan (4 round-bytes at once) ----
    unsigned s = pe;
#pragma unroll
    for (int d = 1; d < 64; d <<= 1) {
        const unsigned o = __shfl_up(s, d, 64);
        if (lane >= d) s = bmax4(s, o);
    }
    unsigned ex = __shfl_up(s, 1, 64);
    if (lane == 0) ex = 0;
    const unsigned bc = __shfl(s, 63, 64);                 // per-round wave totals
    const int wtot = max(max((int)(bc & 255u), (int)((bc >> 8) & 255u)),
                         max((int)((bc >> 16) & 255u), (int)(bc >> 24)));
    s_rmax[wid] = wtot;
    __syncthreads();                                       // B1: pk LUT + wave totals ready

    // carry: second-half wave starts after first half's full max
    const int c0 = half ? s_rmax[wid - 1] : 0;

    // ---- weighted sum (collapsed scan), u32 partial (16 terms < 2^30) ----
    unsigned partial = 0;
    int crun = c0;
#pragma unroll
    for (int i = 0; i < 4; ++i) {
        const int sx   = (int)((ex >> (8 * i)) & 255u);
        int a = max(crun, sx);
#pragma unroll
        for (int k = 0; k < 4; ++k) {
            const int y  = yq[4 * i + k];
            const int h  = (y >> 5) + 8;                   // e8 biased [0,15]
            a = max(a, h);                                 // inclusive prefix max
            const unsigned me4 = s_pk[y + 256];            // me<<4
            partial += (me4 >> (a - h)) << a;              // floor term << (E+8)
        }
        crun = max(crun, (int)((bc >> (8 * i)) & 255u));
    }

    // ---- butterfly reduce within wave (1 u32 step, then u64) ----
    const unsigned ps = partial + __shfl_xor(partial, 1, 64);   // pair < 2^31.1, safe
    unsigned long long p64 = ps;
#pragma unroll
    for (int d = 2; d < 64; d <<= 1) p64 += __shfl_xor(p64, d, 64);
    s_part[wid] = p64;          // every lane has it; benign same-value write
    __syncthreads();            // B2: partials + maxima ready

    const unsigned long long tot = s_part[2 * r] + s_part[2 * r + 1];
    const int      Estar8 = max(s_rmax[2 * r], s_rmax[2 * r + 1]);
    const unsigned msum   = (unsigned)(tot >> Estar8);          // [1024, 2^22)
    const unsigned magic  = (unsigned)(274877906944.0 / (double)msum) + 1u;  // floor(2^38/m)+1

    // ---- per-row fused final LUT: 4 entries per thread (128 threads per row) ----
    const int tr = t & 127;
#pragma unroll
    for (int q = 0; q < 4; ++q) {
        const int      idx  = tr + 128 * q;                // 0..511  (yq = idx-256)
        const unsigned me4  = s_pk[idx];
        const unsigned mout = __umulhi(me4 << 4, magic) >> 6;   // floor(me*256/msum), [0,31]
        const int      e8   = idx >> 5;                        // == (yq>>5)+8
        const int      eoutn = Estar8 - e8;                    // [0,15]
        const int      bl   = 32 - __clz((int)(mout | 1u));
        const int      pw2  = ((mout & (mout - 1u)) == 0u) ? 1 : 0;
        const int      clog = bl - pw2;
        const int      sq   = min(7 - clog, 11 - eoutn);
        const int      rs   = 8 - sq;                          // [1,12]
        const unsigned u    = mout << 8;
        const unsigned bse  = u >> rs;
        const unsigned frac = u & ((1u << rs) - 1u);
        const unsigned hlf  = 1u << (rs - 1);
        unsigned m2 = bse + (((frac > hlf) || (frac == hlf && (bse & 1u))) ? 1u : 0u);
        m2 = min(m2, 127u);
        const int ef = max(clog - eoutn - 4, -8);
        s_fin[r][idx] = (float)m2 * __uint_as_float((unsigned)(ef + 120) << 23);
    }
    __syncthreads();            // B3: final LUTs ready

    // ---- epilogue: one LDS read per element, coalesced float4 stores ----
    float* orow = out + base;
#pragma unroll
    for (int i = 0; i < 4; ++i) {
        float r4[4];
#pragma unroll
        for (int k = 0; k < 4; ++k)
            r4[k] = s_fin[r][yq[4 * i + k] + 256];
        const float4 o4 = {r4[0], r4[1], r4[2], r4[3]};
        *(float4*)(orow + i * 256) = o4;
    }
}

extern "C" void kernel_launch(void* const* d_in, const int* in_sizes, int n_in,
                              void* d_out, int out_size, void* d_ws, size_t ws_size,
                              hipStream_t stream) {
    const float* x = (const float*)d_in[0];
    float*       o = (float*)d_out;
    const int rows = in_sizes[0] / D_DIM;      // 8192
    mxint_softmax_kernel<<<rows / 2, TPB, 0, stream>>>(x, o);
}